// Round 14
// baseline (2793.810 us; speedup 1.0000x reference)
//
#include <hip/hip_runtime.h>
#include <math.h>

#define N_NODESC 50000
#define N_EDGESC 200000
#define N_GRAPHSC 256
#define D_INC 100
#define HD 384
#define STEPSC 4
#define BN_EPS 1e-5f

// deterministic edge aggregation: int32 fixed-point (order-independent sums)
#define FPSCALE 4194304.0f        // 2^22
#define FPINV   (1.0f / 4194304.0f)

#define STATS_ROWS 512
#define STATS_BLOCKS 98           // ceil(50000/512)

typedef _Float16 h8v __attribute__((ext_vector_type(8)));
typedef _Float16 h4v __attribute__((ext_vector_type(4)));
typedef float f4v __attribute__((ext_vector_type(4)));

static __device__ __forceinline__ float sigmoidf_(float x) { return 1.0f / (1.0f + expf(-x)); }

// fp16x2 triple-product MFMA: C += (ah+al)*(bh+bl) dropping al*bl
static __device__ __forceinline__ f4v mfma3(h8v ah, h8v al, h8v bh, h8v bl, f4v c) {
    c = __builtin_amdgcn_mfma_f32_16x16x32_f16(ah, bh, c, 0, 0, 0);
    c = __builtin_amdgcn_mfma_f32_16x16x32_f16(ah, bl, c, 0, 0, 0);
    c = __builtin_amdgcn_mfma_f32_16x16x32_f16(al, bh, c, 0, 0, 0);
    return c;
}

// async global->LDS, 16B per lane; LDS dest = wave-uniform base + lane*16
static __device__ __forceinline__ void gload_lds16(const _Float16* g, _Float16* l) {
    __builtin_amdgcn_global_load_lds(
        (const __attribute__((address_space(1))) unsigned int*)g,
        (__attribute__((address_space(3))) unsigned int*)l, 16, 0, 0);
}

// bijective XCD-chunk swizzle (m204)
static __device__ __forceinline__ int xcd_swz(int orig, int nwg) {
    const int q = nwg >> 3, r = nwg & 7;
    const int xcd = orig & 7, idx = orig >> 3;
    return (xcd < r ? xcd * (q + 1) : r * (q + 1) + (xcd - r) * q) + idx;
}

// ================= fp32 GEMM (K=100 input layer) =================
__global__ __launch_bounds__(256) void gemm64(const float* __restrict__ A,
                                              const float* __restrict__ B,
                                              const float* __restrict__ bias,
                                              float* __restrict__ C,
                                              int M, int K, int N) {
    __shared__ float As[16][68];
    __shared__ float Bs[16][68];
    const int tid = threadIdx.x;
    const int tx = tid & 15, ty = tid >> 4;
    const int m0 = blockIdx.y << 6, n0 = blockIdx.x << 6;
    const int ar = tid >> 2, ac4 = tid & 3;
    const int br = tid >> 4, bc4 = tid & 15;
    float acc[4][4] = {};
    for (int k0 = 0; k0 < K; k0 += 16) {
        float4 av = make_float4(0.f, 0.f, 0.f, 0.f);
        const int arow = m0 + ar, ak = k0 + (ac4 << 2);
        if (arow < M && ak < K) av = *(const float4*)(A + (size_t)arow * K + ak);
        As[(ac4 << 2) + 0][ar] = av.x;
        As[(ac4 << 2) + 1][ar] = av.y;
        As[(ac4 << 2) + 2][ar] = av.z;
        As[(ac4 << 2) + 3][ar] = av.w;
        float4 bv = make_float4(0.f, 0.f, 0.f, 0.f);
        const int bk = k0 + br;
        if (bk < K) bv = *(const float4*)(B + (size_t)bk * N + n0 + (bc4 << 2));
        *(float4*)&Bs[br][bc4 << 2] = bv;
        __syncthreads();
#pragma unroll
        for (int kk = 0; kk < 16; ++kk) {
            const float4 a = *(const float4*)&As[kk][ty << 2];
            const float4 b = *(const float4*)&Bs[kk][tx << 2];
            const float aarr[4] = {a.x, a.y, a.z, a.w};
            const float barr[4] = {b.x, b.y, b.z, b.w};
#pragma unroll
            for (int i = 0; i < 4; ++i)
#pragma unroll
                for (int j = 0; j < 4; ++j) acc[i][j] = fmaf(aarr[i], barr[j], acc[i][j]);
        }
        __syncthreads();
    }
#pragma unroll
    for (int i = 0; i < 4; ++i) {
        const int row = m0 + (ty << 2) + i;
        if (row >= M) continue;
        const int col0 = n0 + (tx << 2);
        float4 out;
        out.x = acc[i][0]; out.y = acc[i][1]; out.z = acc[i][2]; out.w = acc[i][3];
        if (bias) {
            out.x += bias[col0 + 0]; out.y += bias[col0 + 1];
            out.z += bias[col0 + 2]; out.w += bias[col0 + 3];
        }
        *(float4*)(C + (size_t)row * N + col0) = out;
    }
}

// ================= weight prep: fragment-major fp16x2 packing =================
// P[(outer)*512 + lane*8 + e]: each 512-elem (1KB) block is one wave's coalesced
// B-fragment load. lane l, elem e of block (g,jt,kc) =
// W[g*HD + jt*16 + (l&15)][kc*32 + (l>>4)*8 + e].

__global__ __launch_bounds__(256) void pack_gru_w(const float* __restrict__ w,
                                                  _Float16* __restrict__ PH,
                                                  _Float16* __restrict__ PL) {
    const int i = blockIdx.x * 256 + threadIdx.x;  // 3*24*12*64 = 55296
    if (i >= 3 * 24 * 12 * 64) return;
    const int l = i & 63;
    const int kc = (i >> 6) % 12;
    const int jt = ((i >> 6) / 12) % 24;
    const int g = (i >> 6) / (12 * 24);
    const int row = g * HD + jt * 16 + (l & 15);
    const int k0 = kc * 32 + ((l >> 4) << 3);
    const float* s = w + (size_t)row * HD + k0;
    h8v hi, lo;
#pragma unroll
    for (int e = 0; e < 8; ++e) {
        const float v = s[e];
        hi[e] = (_Float16)v;
        lo[e] = (_Float16)(v - (float)hi[e]);
    }
    *(h8v*)(PH + (size_t)i * 8) = hi;
    *(h8v*)(PL + (size_t)i * 8) = lo;
}

__global__ __launch_bounds__(256) void pack_ggc_w(const float* __restrict__ w,
                                                  _Float16* __restrict__ PH,
                                                  _Float16* __restrict__ PL) {
    const int i = blockIdx.x * 256 + threadIdx.x;  // 4*24*12*64 = 73728
    if (i >= STEPSC * 24 * 12 * 64) return;
    const int l = i & 63;
    const int kc = (i >> 6) % 12;
    const int jt = ((i >> 6) / 12) % 24;
    const int s = (i >> 6) / (12 * 24);
    const int n = jt * 16 + (l & 15);
    const int k0 = kc * 32 + ((l >> 4) << 3);
    h8v hi, lo;
#pragma unroll
    for (int e = 0; e < 8; ++e) {
        const float v = w[((size_t)s * HD + k0 + e) * HD + n];
        hi[e] = (_Float16)v;
        lo[e] = (_Float16)(v - (float)hi[e]);
    }
    *(h8v*)(PH + (size_t)i * 8) = hi;
    *(h8v*)(PL + (size_t)i * 8) = lo;
}

// ================= CSR build (once per call; graph constant across steps) =================
__global__ void deg_count(const int* __restrict__ dst, int* __restrict__ deg) {
    const int e = blockIdx.x * 256 + threadIdx.x;
    if (e < N_EDGESC) atomicAdd(&deg[dst[e]], 1);
}

__global__ __launch_bounds__(1024) void scan_deg(const int* __restrict__ deg,
                                                 int* __restrict__ offs) {
    __shared__ int sums[1024];
    const int t = threadIdx.x;
    const int CH = (N_NODESC + 1023) / 1024;  // 49
    const int base = t * CH;
    int s = 0;
    for (int i = 0; i < CH; ++i) {
        const int idx = base + i;
        if (idx < N_NODESC) s += deg[idx];
    }
    sums[t] = s;
    __syncthreads();
    for (int o = 1; o < 1024; o <<= 1) {
        const int v = (t >= o) ? sums[t - o] : 0;
        __syncthreads();
        sums[t] += v;
        __syncthreads();
    }
    int run = (t > 0) ? sums[t - 1] : 0;
    for (int i = 0; i < CH; ++i) {
        const int idx = base + i;
        if (idx < N_NODESC) {
            offs[idx] = run;
            run += deg[idx];
        }
    }
    if (t == 1023) offs[N_NODESC] = run;
}

__global__ void fill_csr(const int* __restrict__ src, const int* __restrict__ dst,
                         const int* __restrict__ offs, int* __restrict__ cursor,
                         int* __restrict__ esrc) {
    const int e = blockIdx.x * 256 + threadIdx.x;
    if (e >= N_EDGESC) return;
    const int d = dst[e];
    const int pos = atomicAdd(&cursor[d], 1);
    esrc[offs[d] + pos] = src[e];
}

// ================= CSR gather + split fused: m halves -> agg halves =================
__global__ __launch_bounds__(256) void gather_agg_h(const _Float16* __restrict__ mH,
                                                    const _Float16* __restrict__ mL,
                                                    const int* __restrict__ offs,
                                                    const int* __restrict__ esrc,
                                                    _Float16* __restrict__ aggH,
                                                    _Float16* __restrict__ aggL) {
    const int gid = blockIdx.x * 256 + threadIdx.x;  // N_NODES*48 exact
    const int n = gid / 48;
    const int c = gid % 48;   // 8-elem chunk
    if (n >= N_NODESC) return;
    const int beg = offs[n], end = offs[n + 1];
    int acc[8] = {};
    for (int i = beg; i < end; ++i) {
        const int s = esrc[i];
        const size_t so = (size_t)s * HD + (c << 3);
        const h8v vh = *(const h8v*)(mH + so);
        const h8v vl = *(const h8v*)(mL + so);
#pragma unroll
        for (int j = 0; j < 8; ++j)
            acc[j] += __float2int_rn(((float)vh[j] + (float)vl[j]) * FPSCALE);
    }
    h8v a, b;
#pragma unroll
    for (int j = 0; j < 8; ++j) {
        const float v = acc[j] * FPINV;
        a[j] = (_Float16)v;
        b[j] = (_Float16)(v - (float)a[j]);
    }
    *(h8v*)(aggH + (size_t)n * HD + (c << 3)) = a;
    *(h8v*)(aggL + (size_t)n * HD + (c << 3)) = b;
}

// ================= dbuf LDS MFMA GEMM (BN=128, 8 waves, wave tile 64x16) =================
// m = h @ ggc_w[s], fp16x2 halves out. Same per-output MFMA k-order -> bit-identical.
__global__ __launch_bounds__(512) void ggc_lds(const _Float16* __restrict__ hH,
                                               const _Float16* __restrict__ hL,
                                               const _Float16* __restrict__ wtH,
                                               const _Float16* __restrict__ wtL,
                                               _Float16* __restrict__ mH,
                                               _Float16* __restrict__ mL) {
    __shared__ _Float16 sH[2][2][64][64];  // [buf][plane][row][k swizzled], 32 KB
    const int tid = threadIdx.x;
    const int wid = tid >> 6, lane = tid & 63;
    const int lr = lane & 15, lk = lane >> 4;
    const int wc = wid;                      // wave column group (16 cols, 8 waves = 128)
    const int wgid = xcd_swz(blockIdx.x, gridDim.x);
    const int row0 = (wgid / 3) << 6, j0 = (wgid % 3) << 7;
    const int sp = wid >> 2;                 // staged plane (0..1)
    const int srbase = (wid & 3) << 4;       // staged row quarter
    const int lrow = lane >> 3, ls = lane & 7;
    const _Float16* splane = sp ? hL : hH;

    f4v acc[4];
    const f4v z4 = {0.f, 0.f, 0.f, 0.f};
    acc[0] = z4; acc[1] = z4; acc[2] = z4; acc[3] = z4;

#define GGC_STAGE(BUF, K0)                                                     \
    _Pragma("unroll")                                                          \
    for (int t2 = 0; t2 < 2; ++t2) {                                           \
        const int row = srbase + (t2 << 3) + lrow;                             \
        const int gk = (K0) + ((ls ^ (row & 7)) << 3);                         \
        const int grow = min(row0 + row, N_NODESC - 1);                        \
        gload_lds16(splane + (size_t)grow * HD + gk,                           \
                    &sH[BUF][sp][srbase + (t2 << 3)][0]);                      \
    }

    GGC_STAGE(0, 0);
    __syncthreads();
    int cur = 0;
    for (int t = 0; t < HD / 64; ++t) {      // 6 k-tiles
        if (t + 1 < HD / 64) GGC_STAGE(cur ^ 1, (t + 1) * 64);
#pragma unroll
        for (int kk = 0; kk < 64; kk += 32) {
            h8v fh[4], fl[4];
#pragma unroll
            for (int sm = 0; sm < 4; ++sm) {
                const int row = sm * 16 + lr;
                const int s8 = (((kk >> 3) + lk) ^ (row & 7)) << 3;
                fh[sm] = *(const h8v*)&sH[cur][0][row][s8];
                fl[sm] = *(const h8v*)&sH[cur][1][row][s8];
            }
            const int kc = t * 2 + (kk >> 5);
            const int jt = (j0 >> 4) + wc;
            const size_t woff = ((size_t)(jt * 12 + kc) << 9) + (lane << 3);
            const h8v bh = *(const h8v*)(wtH + woff);
            const h8v bl = *(const h8v*)(wtL + woff);
            __builtin_amdgcn_s_setprio(1);
#pragma unroll
            for (int sm = 0; sm < 4; ++sm) acc[sm] = mfma3(fh[sm], fl[sm], bh, bl, acc[sm]);
            __builtin_amdgcn_s_setprio(0);
        }
        __syncthreads();
        cur ^= 1;
    }
    const int col = j0 + wc * 16 + lr;
#pragma unroll
    for (int sm = 0; sm < 4; ++sm)
#pragma unroll
        for (int j = 0; j < 4; ++j) {
            const int row = row0 + sm * 16 + lk * 4 + j;
            if (row < N_NODESC) {
                const size_t off = (size_t)row * HD + col;
                const float v = acc[sm][j];
                const _Float16 hh = (_Float16)v;
                mH[off] = hh;
                mL[off] = (_Float16)(v - (float)hh);
            }
        }
#undef GGC_STAGE
}

// ================= dbuf LDS fused GRU (BN=128, 8 waves, wave tile 64x16) =================
__global__ __launch_bounds__(512) void gru_lds(const _Float16* __restrict__ aH,
                                               const _Float16* __restrict__ aL,
                                               const _Float16* __restrict__ hH,
                                               const _Float16* __restrict__ hL,
                                               const _Float16* __restrict__ wihH,
                                               const _Float16* __restrict__ wihL,
                                               const _Float16* __restrict__ whhH,
                                               const _Float16* __restrict__ whhL,
                                               const float* __restrict__ bih,
                                               const float* __restrict__ bhh,
                                               _Float16* __restrict__ oH,
                                               _Float16* __restrict__ oL) {
    __shared__ _Float16 sA[2][4][64][64];  // [buf][plane: aH,aL,hH,hL][row][k], 64 KB
    const int tid = threadIdx.x;
    const int wid = tid >> 6, lane = tid & 63;
    const int lr = lane & 15, lk = lane >> 4;
    const int wc = wid;                     // wave column group (16 cols, 8 waves = 128)
    const int wgid = xcd_swz(blockIdx.x, gridDim.x);
    const int row0 = (wgid / 3) << 6, j0 = (wgid % 3) << 7;
    const int col = j0 + wc * 16 + lr;      // this lane's output column
    const int tmatch = (j0 + wc * 16) >> 6; // k-tile holding this wave's h cols
    const int lctile = (wc * 16 + lr) & 63; // col within that 64-col tile
    const int sp = wid >> 1;                // staged plane (0..3)
    const int srbase = (wid & 1) << 5;      // staged row half
    const int lrow = lane >> 3, ls = lane & 7;
    const _Float16* splane = (sp == 0) ? aH : (sp == 1) ? aL : (sp == 2) ? hH : hL;

    // acc sets: 0=r (gi+gh merged), 1=z (merged), 2=n input part, 3=n hidden part
    f4v acc[4][4];                          // [set][sm]
    const f4v z4 = {0.f, 0.f, 0.f, 0.f};
#pragma unroll
    for (int g = 0; g < 4; ++g)
#pragma unroll
        for (int a = 0; a < 4; ++a) acc[g][a] = z4;
    float hold[4][4];                       // [sm][j]

#define GRU_STAGE(BUF, K0)                                                     \
    _Pragma("unroll")                                                          \
    for (int t4 = 0; t4 < 4; ++t4) {                                           \
        const int row = srbase + (t4 << 3) + lrow;                             \
        const int gk = (K0) + ((ls ^ (row & 7)) << 3);                         \
        const int grow = min(row0 + row, N_NODESC - 1);                        \
        gload_lds16(splane + (size_t)grow * HD + gk,                           \
                    &sA[BUF][sp][srbase + (t4 << 3)][0]);                      \
    }

    GRU_STAGE(0, 0);
    __syncthreads();
    int cur = 0;
    for (int t = 0; t < HD / 64; ++t) {
        if (t + 1 < HD / 64) GRU_STAGE(cur ^ 1, (t + 1) * 64);
#pragma unroll
        for (int kk = 0; kk < 64; kk += 32) {
            h8v fAh[4], fAl[4], fHh[4], fHl[4];
#pragma unroll
            for (int sm = 0; sm < 4; ++sm) {
                const int row = sm * 16 + lr;
                const int s8 = (((kk >> 3) + lk) ^ (row & 7)) << 3;
                fAh[sm] = *(const h8v*)&sA[cur][0][row][s8];
                fAl[sm] = *(const h8v*)&sA[cur][1][row][s8];
                fHh[sm] = *(const h8v*)&sA[cur][2][row][s8];
                fHl[sm] = *(const h8v*)&sA[cur][3][row][s8];
            }
            const int kc = t * 2 + (kk >> 5);
            const int jt = (j0 >> 4) + wc;
#pragma unroll
            for (int g = 0; g < 3; ++g) {
                const size_t woff = ((size_t)((g * 24 + jt) * 12 + kc) << 9) + (lane << 3);
                const h8v BiH = *(const h8v*)(wihH + woff);
                const h8v BiL = *(const h8v*)(wihL + woff);
                const h8v BhH = *(const h8v*)(whhH + woff);
                const h8v BhL = *(const h8v*)(whhL + woff);
                __builtin_amdgcn_s_setprio(1);
                if (g < 2) {
#pragma unroll
                    for (int sm = 0; sm < 4; ++sm) {
                        acc[g][sm] = mfma3(fAh[sm], fAl[sm], BiH, BiL, acc[g][sm]);
                        acc[g][sm] = mfma3(fHh[sm], fHl[sm], BhH, BhL, acc[g][sm]);
                    }
                } else {
#pragma unroll
                    for (int sm = 0; sm < 4; ++sm) {
                        acc[2][sm] = mfma3(fAh[sm], fAl[sm], BiH, BiL, acc[2][sm]);
                        acc[3][sm] = mfma3(fHh[sm], fHl[sm], BhH, BhL, acc[3][sm]);
                    }
                }
                __builtin_amdgcn_s_setprio(0);
            }
        }
        // capture hold = hH+hL at (row, col) from the staged tile (bit-identical
        // to a global read; this wave's cols are resident exactly at t == tmatch)
        if (t == tmatch) {
#pragma unroll
            for (int sm = 0; sm < 4; ++sm)
#pragma unroll
                for (int j = 0; j < 4; ++j) {
                    const int row = sm * 16 + lk * 4 + j;
                    const int sc = (((lctile >> 3) ^ (row & 7)) << 3) | (lctile & 7);
                    hold[sm][j] = (float)sA[cur][2][row][sc] + (float)sA[cur][3][row][sc];
                }
        }
        __syncthreads();
        cur ^= 1;
    }
    // epilogue: gates + GRU update
    const float brz = bih[col] + bhh[col];
    const float bzz = bih[HD + col] + bhh[HD + col];
    const float bni = bih[2 * HD + col];
    const float bnh = bhh[2 * HD + col];
#pragma unroll
    for (int sm = 0; sm < 4; ++sm)
#pragma unroll
        for (int j = 0; j < 4; ++j) {
            const int row = row0 + sm * 16 + lk * 4 + j;
            if (row < N_NODESC) {
                const size_t off = (size_t)row * HD + col;
                const float r = sigmoidf_(acc[0][sm][j] + brz);
                const float z = sigmoidf_(acc[1][sm][j] + bzz);
                const float n = tanhf((acc[2][sm][j] + bni) + r * (acc[3][sm][j] + bnh));
                const float res = (1.f - z) * n + z * hold[sm][j];
                const _Float16 hh = (_Float16)res;
                oH[off] = hh;
                oL[off] = (_Float16)(res - (float)hh);
            }
        }
#undef GRU_STAGE
}

// ================= BN stats (deterministic two-stage) =================
__global__ __launch_bounds__(384) void col_stats_partial(const float* __restrict__ X, int M,
                                                         float* __restrict__ pS,
                                                         float* __restrict__ pQ) {
    const int f = threadIdx.x;
    const int b = blockIdx.x;
    const int r0 = b * STATS_ROWS;
    const int r1 = min(r0 + STATS_ROWS, M);
    float s = 0.f, q = 0.f;
    for (int r = r0; r < r1; ++r) {
        const float v = X[(size_t)r * HD + f];
        s += v;
        q += v * v;
    }
    pS[b * HD + f] = s;
    pQ[b * HD + f] = q;
}

__global__ __launch_bounds__(384) void col_stats_h(const _Float16* __restrict__ hH,
                                                   const _Float16* __restrict__ hL, int M,
                                                   float* __restrict__ pS,
                                                   float* __restrict__ pQ) {
    const int f = threadIdx.x;
    const int b = blockIdx.x;
    const int r0 = b * STATS_ROWS;
    const int r1 = min(r0 + STATS_ROWS, M);
    float s = 0.f, q = 0.f;
    for (int r = r0; r < r1; ++r) {
        const size_t off = (size_t)r * HD + f;
        const float v = (float)hH[off] + (float)hL[off];
        s += v;
        q += v * v;
    }
    pS[b * HD + f] = s;
    pQ[b * HD + f] = q;
}

__global__ void bn_stats_final(const float* __restrict__ pS, const float* __restrict__ pQ,
                               const float* __restrict__ g, const float* __restrict__ b,
                               float* __restrict__ scale, float* __restrict__ shift, float invM) {
    const int f = threadIdx.x;
    float s = 0.f, q = 0.f;
    for (int blk = 0; blk < STATS_BLOCKS; ++blk) {
        s += pS[blk * HD + f];
        q += pQ[blk * HD + f];
    }
    const float mean = s * invM;
    const float var = q * invM - mean * mean;
    const float sc = g[f] * rsqrtf(var + BN_EPS);
    scale[f] = sc;
    shift[f] = b[f] - mean * sc;
}

// relu(X*scale+shift) -> hi/lo halves
__global__ __launch_bounds__(256) void bn_relu_split(const float* __restrict__ X,
                                                     const float* __restrict__ scale,
                                                     const float* __restrict__ shift,
                                                     _Float16* __restrict__ hH,
                                                     _Float16* __restrict__ hL) {
    const size_t i4 = (size_t)blockIdx.x * 256 + threadIdx.x;  // NH/4 exact
    const int f = (int)((i4 * 4) % HD);
    const float4 v = ((const float4*)X)[i4];
    float r0 = fmaxf(fmaf(v.x, scale[f + 0], shift[f + 0]), 0.f);
    float r1 = fmaxf(fmaf(v.y, scale[f + 1], shift[f + 1]), 0.f);
    float r2 = fmaxf(fmaf(v.z, scale[f + 2], shift[f + 2]), 0.f);
    float r3 = fmaxf(fmaf(v.w, scale[f + 3], shift[f + 3]), 0.f);
    h4v a, b;
    a[0] = (_Float16)r0; b[0] = (_Float16)(r0 - (float)a[0]);
    a[1] = (_Float16)r1; b[1] = (_Float16)(r1 - (float)a[1]);
    a[2] = (_Float16)r2; b[2] = (_Float16)(r2 - (float)a[2]);
    a[3] = (_Float16)r3; b[3] = (_Float16)(r3 - (float)a[3]);
    *(h4v*)(hH + i4 * 4) = a;
    *(h4v*)(hL + i4 * 4) = b;
}

// hfinal = relu((hH+hL)*scale + shift + relu(G*scale1 + shift1))  (fused skip)
__global__ __launch_bounds__(256) void bn_skip_relu_h2(const _Float16* __restrict__ hH,
                                                       const _Float16* __restrict__ hL,
                                                       const float* __restrict__ scale,
                                                       const float* __restrict__ shift,
                                                       const float* __restrict__ G,
                                                       const float* __restrict__ scale1,
                                                       const float* __restrict__ shift1,
                                                       float* __restrict__ out) {
    const size_t i4 = (size_t)blockIdx.x * 256 + threadIdx.x;
    const int f = (int)((i4 * 4) % HD);
    const h4v a = *(const h4v*)(hH + i4 * 4);
    const h4v b = *(const h4v*)(hL + i4 * 4);
    const float4 g = ((const float4*)G)[i4];
    const float s0 = fmaxf(fmaf(g.x, scale1[f + 0], shift1[f + 0]), 0.f);
    const float s1 = fmaxf(fmaf(g.y, scale1[f + 1], shift1[f + 1]), 0.f);
    const float s2 = fmaxf(fmaf(g.z, scale1[f + 2], shift1[f + 2]), 0.f);
    const float s3 = fmaxf(fmaf(g.w, scale1[f + 3], shift1[f + 3]), 0.f);
    float4 r;
    r.x = fmaxf(fmaf((float)a[0] + (float)b[0], scale[f + 0], shift[f + 0]) + s0, 0.f);
    r.y = fmaxf(fmaf((float)a[1] + (float)b[1], scale[f + 1], shift[f + 1]) + s1, 0.f);
    r.z = fmaxf(fmaf((float)a[2] + (float)b[2], scale[f + 2], shift[f + 2]) + s2, 0.f);
    r.w = fmaxf(fmaf((float)a[3] + (float)b[3], scale[f + 3], shift[f + 3]) + s3, 0.f);
    ((float4*)out)[i4] = r;
}

// ================= attention pooling + head =================
__global__ __launch_bounds__(64) void att_logits(const float* __restrict__ h2,
                                                 const float* __restrict__ att_w,
                                                 const float* __restrict__ att_b,
                                                 float* __restrict__ logits) {
    const int n = blockIdx.x;
    const int l = threadIdx.x;
    float acc = 0.f;
#pragma unroll
    for (int k = 0; k < HD; k += 64) acc += h2[(size_t)n * HD + k + l] * att_w[k + l];
#pragma unroll
    for (int o = 32; o > 0; o >>= 1) acc += __shfl_down(acc, o);
    if (l == 0) logits[n] = acc + att_b[0];
}

__global__ void count_graphs(const int* __restrict__ batch, int* __restrict__ counts) {
    const int n = blockIdx.x * 256 + threadIdx.x;
    if (n < N_NODESC) atomicAdd(&counts[batch[n]], 1);
}

__global__ void scan_offsets(const int* __restrict__ counts, int* __restrict__ offs) {
    __shared__ int tmp[N_GRAPHSC];
    const int t = threadIdx.x;
    tmp[t] = counts[t];
    __syncthreads();
    for (int o = 1; o < N_GRAPHSC; o <<= 1) {
        int v = (t >= o) ? tmp[t - o] : 0;
        __syncthreads();
        tmp[t] += v;
        __syncthreads();
    }
    offs[t] = tmp[t] - counts[t];
}

__global__ __launch_bounds__(384) void pool_graphs(const float* __restrict__ h2,
                                                   const float* __restrict__ logits,
                                                   const int* __restrict__ offs,
                                                   const int* __restrict__ counts,
                                                   float* __restrict__ pooled) {
    const int g = blockIdx.x;
    const int t = threadIdx.x;
    const int s = offs[g], c = counts[g], e = s + c;
    __shared__ float red[384];
    float mx = -1e30f;
    for (int n = s + t; n < e; n += 384) mx = fmaxf(mx, logits[n]);
    red[t] = mx;
    __syncthreads();
    if (t < 128) red[t] = fmaxf(red[t], fmaxf(red[t + 128], red[t + 256]));
    __syncthreads();
    for (int w = 64; w > 0; w >>= 1) {
        if (t < w) red[t] = fmaxf(red[t], red[t + w]);
        __syncthreads();
    }
    mx = red[0];
    __syncthreads();
    float sm = 0.f;
    for (int n = s + t; n < e; n += 384) sm += expf(logits[n] - mx);
    red[t] = sm;
    __syncthreads();
    if (t < 128) red[t] += red[t + 128] + red[t + 256];
    __syncthreads();
    for (int w = 64; w > 0; w >>= 1) {
        if (t < w) red[t] += red[t + w];
        __syncthreads();
    }
    const float denom = red[0];
    const float inv = (c > 0) ? 1.0f / denom : 0.0f;
    float acc = 0.f;
    for (int n = s; n < e; ++n) acc += expf(logits[n] - mx) * h2[(size_t)n * HD + t];
    pooled[(size_t)g * HD + t] = acc * inv;
}

__global__ void fc_small(const float* __restrict__ X, const float* __restrict__ W,
                         const float* __restrict__ bias, float* __restrict__ Y,
                         int K, int N) {
    const int m = blockIdx.x;
    const int n = threadIdx.x;
    if (n >= N) return;
    float acc = bias[n];
    for (int k = 0; k < K; ++k) acc += X[m * K + k] * W[k * N + n];
    Y[m * N + n] = acc;
}

__global__ void bn_small_relu(float* X, int M, int N,
                              const float* __restrict__ g, const float* __restrict__ b) {
    const int f = threadIdx.x;
    if (f >= N) return;
    float s = 0.f, q = 0.f;
    for (int r = 0; r < M; ++r) {
        const float v = X[r * N + f];
        s += v;
        q += v * v;
    }
    const float mean = s / M;
    const float var = q / M - mean * mean;
    const float sc = g[f] * rsqrtf(var + BN_EPS);
    const float sh = b[f] - mean * sc;
    for (int r = 0; r < M; ++r) X[r * N + f] = fmaxf(X[r * N + f] * sc + sh, 0.f);
}

extern "C" void kernel_launch(void* const* d_in, const int* in_sizes, int n_in,
                              void* d_out, int out_size, void* d_ws, size_t ws_size,
                              hipStream_t stream) {
    const float* x       = (const float*)d_in[0];
    const int*   eidx    = (const int*)d_in[1];
    const int*   batch   = (const int*)d_in[2];
    const float* w_in    = (const float*)d_in[3];
    const float* b_in    = (const float*)d_in[4];
    const float* bn1_g   = (const float*)d_in[5];
    const float* bn1_b   = (const float*)d_in[6];
    const float* ggc_w   = (const float*)d_in[7];
    const float* gru_wih = (const float*)d_in[8];
    const float* gru_whh = (const float*)d_in[9];
    const float* gru_bih = (const float*)d_in[10];
    const float* gru_bhh = (const float*)d_in[11];
    const float* bn2_g   = (const float*)d_in[12];
    const float* bn2_b   = (const float*)d_in[13];
    const float* att_w   = (const float*)d_in[14];
    const float* att_b   = (const float*)d_in[15];
    const float* fc1_w   = (const float*)d_in[16];
    const float* fc1_b   = (const float*)d_in[17];
    const float* bn3_g   = (const float*)d_in[18];
    const float* bn3_b   = (const float*)d_in[19];
    const float* fc2_w   = (const float*)d_in[20];
    const float* fc2_b   = (const float*)d_in[21];
    const float* bn4_g   = (const float*)d_in[22];
    const float* bn4_b   = (const float*)d_in[23];
    const float* fc3_w   = (const float*)d_in[24];
    const float* fc3_b   = (const float*)d_in[25];

    const int* src = eidx;
    const int* dst = eidx + N_EDGESC;

    // ---- workspace carve (~239 MB) ----
    const size_t NH = (size_t)N_NODESC * HD;  // 19.2M elems
    char* p = (char*)d_ws;
    float* R0 = (float*)p; p += NH * sizeof(float);   // rotating region 0
    float* R1 = (float*)p; p += NH * sizeof(float);   // rotating region 1
    float* Mreg = (float*)p; p += NH * sizeof(float); // agg halves / hfinal
    _Float16* wihP_H = (_Float16*)p; p += 3 * HD * HD * sizeof(_Float16);
    _Float16* wihP_L = (_Float16*)p; p += 3 * HD * HD * sizeof(_Float16);
    _Float16* whhP_H = (_Float16*)p; p += 3 * HD * HD * sizeof(_Float16);
    _Float16* whhP_L = (_Float16*)p; p += 3 * HD * HD * sizeof(_Float16);
    _Float16* ggcP_H = (_Float16*)p; p += (size_t)STEPSC * HD * HD * sizeof(_Float16);
    _Float16* ggcP_L = (_Float16*)p; p += (size_t)STEPSC * HD * HD * sizeof(_Float16);
    float* logits = (float*)p; p += N_NODESC * sizeof(float);
    float* pS = (float*)p; p += STATS_BLOCKS * HD * sizeof(float);
    float* pQ = (float*)p; p += STATS_BLOCKS * HD * sizeof(float);
    float* scale  = (float*)p; p += HD * sizeof(float);
    float* shift  = (float*)p; p += HD * sizeof(float);
    float* scale1 = (float*)p; p += HD * sizeof(float);
    float* shift1 = (float*)p; p += HD * sizeof(float);
    float* pooled = (float*)p; p += N_GRAPHSC * HD * sizeof(float);
    float* y1 = (float*)p; p += N_GRAPHSC * HD * sizeof(float);
    float* y2 = (float*)p; p += N_GRAPHSC * (HD / 2) * sizeof(float);
    int* counts = (int*)p; p += N_GRAPHSC * sizeof(int);
    int* offs = (int*)p; p += N_GRAPHSC * sizeof(int);
    // CSR (built once per call)
    int* deg    = (int*)p; p += N_NODESC * sizeof(int);
    int* eoffs  = (int*)p; p += (N_NODESC + 1) * sizeof(int);
    int* cursor = (int*)p; p += N_NODESC * sizeof(int);
    int* esrc   = (int*)p; p += N_EDGESC * sizeof(int);

    const int nwg = 3 * ((N_NODESC + 63) / 64);  // 3*782 = 2346 (BN=128)
    const int ew_blocks = (int)(NH / 4 / 256);   // 18750 exact

    // 0a) CSR build (graph constant across all 4 steps)
    hipMemsetAsync(deg, 0, N_NODESC * sizeof(int), stream);
    hipMemsetAsync(cursor, 0, N_NODESC * sizeof(int), stream);
    deg_count<<<(N_EDGESC + 255) / 256, 256, 0, stream>>>(dst, deg);
    scan_deg<<<1, 1024, 0, stream>>>(deg, eoffs);
    fill_csr<<<(N_EDGESC + 255) / 256, 256, 0, stream>>>(src, dst, eoffs, cursor, esrc);

    // 0b) weight prep: fragment-major packed fp16x2 (deterministic)
    pack_gru_w<<<(3 * 24 * 12 * 64 + 255) / 256, 256, 0, stream>>>(gru_wih, wihP_H, wihP_L);
    pack_gru_w<<<(3 * 24 * 12 * 64 + 255) / 256, 256, 0, stream>>>(gru_whh, whhP_H, whhP_L);
    pack_ggc_w<<<(STEPSC * 24 * 12 * 64 + 255) / 256, 256, 0, stream>>>(ggc_w, ggcP_H, ggcP_L);

    // 1) input layer (fp32) + bn1 -> h halves in R1
    gemm64<<<dim3(HD / 64, (N_NODESC + 63) / 64), 256, 0, stream>>>(x, w_in, b_in, R0,
                                                                    N_NODESC, D_INC, HD);
    col_stats_partial<<<STATS_BLOCKS, 384, 0, stream>>>(R0, N_NODESC, pS, pQ);
    bn_stats_final<<<1, 384, 0, stream>>>(pS, pQ, bn1_g, bn1_b, scale1, shift1, 1.0f / N_NODESC);
    bn_relu_split<<<ew_blocks, 256, 0, stream>>>(R0, scale1, shift1, (_Float16*)R1,
                                                 (_Float16*)R1 + NH);

    // 2) GatedGraphConv loop: ggc -> m halves (Oth); gather -> agg halves (Mreg);
    //    gru -> h' halves (Oth, overwrites m); rotate.
    float* Hcur = R1;
    float* Oth = R0;
    _Float16* aggH = (_Float16*)Mreg;
    _Float16* aggL = aggH + NH;
    for (int s7 = 0; s7 < STEPSC; ++s7) {
        const _Float16* hcH = (const _Float16*)Hcur;
        const _Float16* hcL = (const _Float16*)Hcur + NH;
        _Float16* mH = (_Float16*)Oth;
        _Float16* mL = mH + NH;
        ggc_lds<<<nwg, 512, 0, stream>>>(hcH, hcL,
                                         ggcP_H + (size_t)s7 * HD * HD,
                                         ggcP_L + (size_t)s7 * HD * HD, mH, mL);
        gather_agg_h<<<(N_NODESC * 48) / 256 + 1, 256, 0, stream>>>(mH, mL, eoffs, esrc,
                                                                    aggH, aggL);
        gru_lds<<<nwg, 512, 0, stream>>>(aggH, aggL, hcH, hcL, wihP_H, wihP_L, whhP_H, whhP_L,
                                         gru_bih, gru_bhh, mH, mL);  // oH/oL overwrite m
        float* t = Hcur; Hcur = Oth; Oth = t;
    }

    // 3) bn2 + skip recompute (fused into one elementwise pass) -> hfinal (Mreg)
    const _Float16* hfH = (const _Float16*)Hcur;
    const _Float16* hfL = (const _Float16*)Hcur + NH;
    col_stats_h<<<STATS_BLOCKS, 384, 0, stream>>>(hfH, hfL, N_NODESC, pS, pQ);
    bn_stats_final<<<1, 384, 0, stream>>>(pS, pQ, bn2_g, bn2_b, scale, shift, 1.0f / N_NODESC);
    gemm64<<<dim3(HD / 64, (N_NODESC + 63) / 64), 256, 0, stream>>>(x, w_in, b_in, Oth,
                                                                    N_NODESC, D_INC, HD);
    float* hfinal = Mreg;
    bn_skip_relu_h2<<<ew_blocks, 256, 0, stream>>>(hfH, hfL, scale, shift, Oth,
                                                   scale1, shift1, hfinal);

    // 4) attention pooling
    att_logits<<<N_NODESC, 64, 0, stream>>>(hfinal, att_w, att_b, logits);
    hipMemsetAsync(counts, 0, N_GRAPHSC * sizeof(int), stream);
    count_graphs<<<(N_NODESC + 255) / 256, 256, 0, stream>>>(batch, counts);
    scan_offsets<<<1, N_GRAPHSC, 0, stream>>>(counts, offs);
    pool_graphs<<<N_GRAPHSC, 384, 0, stream>>>(hfinal, logits, offs, counts, pooled);

    // 5) MLP head
    fc_small<<<N_GRAPHSC, 384, 0, stream>>>(pooled, fc1_w, fc1_b, y1, HD, HD);
    bn_small_relu<<<1, 384, 0, stream>>>(y1, N_GRAPHSC, HD, bn3_g, bn3_b);
    fc_small<<<N_GRAPHSC, 192, 0, stream>>>(y1, fc2_w, fc2_b, y2, HD, HD / 2);
    bn_small_relu<<<1, 192, 0, stream>>>(y2, N_GRAPHSC, HD / 2, bn4_g, bn4_b);
    fc_small<<<N_GRAPHSC, 64, 0, stream>>>(y2, fc3_w, fc3_b, (float*)d_out, HD / 2, 2);
}

// Round 15
// 2771.222 us; speedup vs baseline: 1.0082x; 1.0082x over previous
//
#include <hip/hip_runtime.h>
#include <math.h>

#define N_NODESC 50000
#define N_EDGESC 200000
#define N_GRAPHSC 256
#define D_INC 100
#define HD 384
#define STEPSC 4
#define BN_EPS 1e-5f

// deterministic edge aggregation: int32 fixed-point (order-independent sums)
#define FPSCALE 4194304.0f        // 2^22
#define FPINV   (1.0f / 4194304.0f)

#define STATS_ROWS 512
#define STATS_BLOCKS 98           // ceil(50000/512)

typedef _Float16 h8v __attribute__((ext_vector_type(8)));
typedef _Float16 h4v __attribute__((ext_vector_type(4)));
typedef _Float16 h2v __attribute__((ext_vector_type(2)));
typedef float f4v __attribute__((ext_vector_type(4)));

static __device__ __forceinline__ float sigmoidf_(float x) { return 1.0f / (1.0f + expf(-x)); }

// fp16x2 triple-product MFMA: C += (ah+al)*(bh+bl) dropping al*bl
static __device__ __forceinline__ f4v mfma3(h8v ah, h8v al, h8v bh, h8v bl, f4v c) {
    c = __builtin_amdgcn_mfma_f32_16x16x32_f16(ah, bh, c, 0, 0, 0);
    c = __builtin_amdgcn_mfma_f32_16x16x32_f16(ah, bl, c, 0, 0, 0);
    c = __builtin_amdgcn_mfma_f32_16x16x32_f16(al, bh, c, 0, 0, 0);
    return c;
}

// async global->LDS, 16B per lane; LDS dest = wave-uniform base + lane*16
static __device__ __forceinline__ void gload_lds16(const _Float16* g, _Float16* l) {
    __builtin_amdgcn_global_load_lds(
        (const __attribute__((address_space(1))) unsigned int*)g,
        (__attribute__((address_space(3))) unsigned int*)l, 16, 0, 0);
}

// bijective XCD-chunk swizzle (m204)
static __device__ __forceinline__ int xcd_swz(int orig, int nwg) {
    const int q = nwg >> 3, r = nwg & 7;
    const int xcd = orig & 7, idx = orig >> 3;
    return (xcd < r ? xcd * (q + 1) : r * (q + 1) + (xcd - r) * q) + idx;
}

// ================= fp32 GEMM (K=100 input layer) =================
__global__ __launch_bounds__(256) void gemm64(const float* __restrict__ A,
                                              const float* __restrict__ B,
                                              const float* __restrict__ bias,
                                              float* __restrict__ C,
                                              int M, int K, int N) {
    __shared__ float As[16][68];
    __shared__ float Bs[16][68];
    const int tid = threadIdx.x;
    const int tx = tid & 15, ty = tid >> 4;
    const int m0 = blockIdx.y << 6, n0 = blockIdx.x << 6;
    const int ar = tid >> 2, ac4 = tid & 3;
    const int br = tid >> 4, bc4 = tid & 15;
    float acc[4][4] = {};
    for (int k0 = 0; k0 < K; k0 += 16) {
        float4 av = make_float4(0.f, 0.f, 0.f, 0.f);
        const int arow = m0 + ar, ak = k0 + (ac4 << 2);
        if (arow < M && ak < K) av = *(const float4*)(A + (size_t)arow * K + ak);
        As[(ac4 << 2) + 0][ar] = av.x;
        As[(ac4 << 2) + 1][ar] = av.y;
        As[(ac4 << 2) + 2][ar] = av.z;
        As[(ac4 << 2) + 3][ar] = av.w;
        float4 bv = make_float4(0.f, 0.f, 0.f, 0.f);
        const int bk = k0 + br;
        if (bk < K) bv = *(const float4*)(B + (size_t)bk * N + n0 + (bc4 << 2));
        *(float4*)&Bs[br][bc4 << 2] = bv;
        __syncthreads();
#pragma unroll
        for (int kk = 0; kk < 16; ++kk) {
            const float4 a = *(const float4*)&As[kk][ty << 2];
            const float4 b = *(const float4*)&Bs[kk][tx << 2];
            const float aarr[4] = {a.x, a.y, a.z, a.w};
            const float barr[4] = {b.x, b.y, b.z, b.w};
#pragma unroll
            for (int i = 0; i < 4; ++i)
#pragma unroll
                for (int j = 0; j < 4; ++j) acc[i][j] = fmaf(aarr[i], barr[j], acc[i][j]);
        }
        __syncthreads();
    }
#pragma unroll
    for (int i = 0; i < 4; ++i) {
        const int row = m0 + (ty << 2) + i;
        if (row >= M) continue;
        const int col0 = n0 + (tx << 2);
        float4 out;
        out.x = acc[i][0]; out.y = acc[i][1]; out.z = acc[i][2]; out.w = acc[i][3];
        if (bias) {
            out.x += bias[col0 + 0]; out.y += bias[col0 + 1];
            out.z += bias[col0 + 2]; out.w += bias[col0 + 3];
        }
        *(float4*)(C + (size_t)row * N + col0) = out;
    }
}

// ================= weight prep: fragment-major fp16x2 packing =================
__global__ __launch_bounds__(256) void pack_gru_w(const float* __restrict__ w,
                                                  _Float16* __restrict__ PH,
                                                  _Float16* __restrict__ PL) {
    const int i = blockIdx.x * 256 + threadIdx.x;  // 3*24*12*64 = 55296
    if (i >= 3 * 24 * 12 * 64) return;
    const int l = i & 63;
    const int kc = (i >> 6) % 12;
    const int jt = ((i >> 6) / 12) % 24;
    const int g = (i >> 6) / (12 * 24);
    const int row = g * HD + jt * 16 + (l & 15);
    const int k0 = kc * 32 + ((l >> 4) << 3);
    const float* s = w + (size_t)row * HD + k0;
    h8v hi, lo;
#pragma unroll
    for (int e = 0; e < 8; ++e) {
        const float v = s[e];
        hi[e] = (_Float16)v;
        lo[e] = (_Float16)(v - (float)hi[e]);
    }
    *(h8v*)(PH + (size_t)i * 8) = hi;
    *(h8v*)(PL + (size_t)i * 8) = lo;
}

__global__ __launch_bounds__(256) void pack_ggc_w(const float* __restrict__ w,
                                                  _Float16* __restrict__ PH,
                                                  _Float16* __restrict__ PL) {
    const int i = blockIdx.x * 256 + threadIdx.x;  // 4*24*12*64 = 73728
    if (i >= STEPSC * 24 * 12 * 64) return;
    const int l = i & 63;
    const int kc = (i >> 6) % 12;
    const int jt = ((i >> 6) / 12) % 24;
    const int s = (i >> 6) / (12 * 24);
    const int n = jt * 16 + (l & 15);
    const int k0 = kc * 32 + ((l >> 4) << 3);
    h8v hi, lo;
#pragma unroll
    for (int e = 0; e < 8; ++e) {
        const float v = w[((size_t)s * HD + k0 + e) * HD + n];
        hi[e] = (_Float16)v;
        lo[e] = (_Float16)(v - (float)hi[e]);
    }
    *(h8v*)(PH + (size_t)i * 8) = hi;
    *(h8v*)(PL + (size_t)i * 8) = lo;
}

// ================= CSR build (once per call; graph constant across steps) =================
__global__ void deg_count(const int* __restrict__ dst, int* __restrict__ deg) {
    const int e = blockIdx.x * 256 + threadIdx.x;
    if (e < N_EDGESC) atomicAdd(&deg[dst[e]], 1);
}

__global__ __launch_bounds__(1024) void scan_deg(const int* __restrict__ deg,
                                                 int* __restrict__ offs) {
    __shared__ int sums[1024];
    const int t = threadIdx.x;
    const int CH = (N_NODESC + 1023) / 1024;  // 49
    const int base = t * CH;
    int s = 0;
    for (int i = 0; i < CH; ++i) {
        const int idx = base + i;
        if (idx < N_NODESC) s += deg[idx];
    }
    sums[t] = s;
    __syncthreads();
    for (int o = 1; o < 1024; o <<= 1) {
        const int v = (t >= o) ? sums[t - o] : 0;
        __syncthreads();
        sums[t] += v;
        __syncthreads();
    }
    int run = (t > 0) ? sums[t - 1] : 0;
    for (int i = 0; i < CH; ++i) {
        const int idx = base + i;
        if (idx < N_NODESC) {
            offs[idx] = run;
            run += deg[idx];
        }
    }
    if (t == 1023) offs[N_NODESC] = run;
}

__global__ void fill_csr(const int* __restrict__ src, const int* __restrict__ dst,
                         const int* __restrict__ offs, int* __restrict__ cursor,
                         int* __restrict__ esrc) {
    const int e = blockIdx.x * 256 + threadIdx.x;
    if (e >= N_EDGESC) return;
    const int d = dst[e];
    const int pos = atomicAdd(&cursor[d], 1);
    esrc[offs[d] + pos] = src[e];
}

// ================= CSR gather + split fused: interleaved m -> agg halves =================
// m is pair-interleaved ({hi,lo} per element): each edge-chunk read is one
// contiguous, 64B-aligned 64B line. int accumulation = order-independent.
__global__ __launch_bounds__(256) void gather_agg_h(const _Float16* __restrict__ mHL,
                                                    const int* __restrict__ offs,
                                                    const int* __restrict__ esrc,
                                                    _Float16* __restrict__ aggH,
                                                    _Float16* __restrict__ aggL) {
    const int gid = blockIdx.x * 256 + threadIdx.x;  // N_NODES*24
    const int n = gid / 24;
    const int c = gid % 24;   // 16-elem chunk
    if (n >= N_NODESC) return;
    const int beg = offs[n], end = offs[n + 1];
    int acc[16] = {};
    for (int i = beg; i < end; ++i) {
        const int s = esrc[i];
        const size_t so = ((size_t)s * HD + (c << 4)) * 2;  // halves offset (64B line)
        const h8v v0 = *(const h8v*)(mHL + so);
        const h8v v1 = *(const h8v*)(mHL + so + 8);
        const h8v v2 = *(const h8v*)(mHL + so + 16);
        const h8v v3 = *(const h8v*)(mHL + so + 24);
#pragma unroll
        for (int j = 0; j < 4; ++j) {
            acc[j + 0]  += __float2int_rn(((float)v0[2 * j] + (float)v0[2 * j + 1]) * FPSCALE);
            acc[j + 4]  += __float2int_rn(((float)v1[2 * j] + (float)v1[2 * j + 1]) * FPSCALE);
            acc[j + 8]  += __float2int_rn(((float)v2[2 * j] + (float)v2[2 * j + 1]) * FPSCALE);
            acc[j + 12] += __float2int_rn(((float)v3[2 * j] + (float)v3[2 * j + 1]) * FPSCALE);
        }
    }
    h8v a0, a1, b0, b1;
#pragma unroll
    for (int j = 0; j < 8; ++j) {
        float v = acc[j] * FPINV;
        a0[j] = (_Float16)v;
        b0[j] = (_Float16)(v - (float)a0[j]);
        v = acc[j + 8] * FPINV;
        a1[j] = (_Float16)v;
        b1[j] = (_Float16)(v - (float)a1[j]);
    }
    const size_t oo = (size_t)n * HD + (c << 4);
    *(h8v*)(aggH + oo) = a0;
    *(h8v*)(aggH + oo + 8) = a1;
    *(h8v*)(aggL + oo) = b0;
    *(h8v*)(aggL + oo + 8) = b1;
}

// ================= dbuf LDS MFMA GEMM (BN=128, 8 waves, wave tile 64x16) =================
// m = h @ ggc_w[s]; output PAIR-INTERLEAVED {hi,lo} (consumed only by gather).
__global__ __launch_bounds__(512) void ggc_lds(const _Float16* __restrict__ hH,
                                               const _Float16* __restrict__ hL,
                                               const _Float16* __restrict__ wtH,
                                               const _Float16* __restrict__ wtL,
                                               _Float16* __restrict__ mHL) {
    __shared__ _Float16 sH[2][2][64][64];  // [buf][plane][row][k swizzled], 32 KB
    const int tid = threadIdx.x;
    const int wid = tid >> 6, lane = tid & 63;
    const int lr = lane & 15, lk = lane >> 4;
    const int wc = wid;                      // wave column group (16 cols, 8 waves = 128)
    const int wgid = xcd_swz(blockIdx.x, gridDim.x);
    const int row0 = (wgid / 3) << 6, j0 = (wgid % 3) << 7;
    const int sp = wid >> 2;                 // staged plane (0..1)
    const int srbase = (wid & 3) << 4;       // staged row quarter
    const int lrow = lane >> 3, ls = lane & 7;
    const _Float16* splane = sp ? hL : hH;

    f4v acc[4];
    const f4v z4 = {0.f, 0.f, 0.f, 0.f};
    acc[0] = z4; acc[1] = z4; acc[2] = z4; acc[3] = z4;

#define GGC_STAGE(BUF, K0)                                                     \
    _Pragma("unroll")                                                          \
    for (int t2 = 0; t2 < 2; ++t2) {                                           \
        const int row = srbase + (t2 << 3) + lrow;                             \
        const int gk = (K0) + ((ls ^ (row & 7)) << 3);                         \
        const int grow = min(row0 + row, N_NODESC - 1);                        \
        gload_lds16(splane + (size_t)grow * HD + gk,                           \
                    &sH[BUF][sp][srbase + (t2 << 3)][0]);                      \
    }

    GGC_STAGE(0, 0);
    __syncthreads();
    int cur = 0;
    for (int t = 0; t < HD / 64; ++t) {      // 6 k-tiles
        if (t + 1 < HD / 64) GGC_STAGE(cur ^ 1, (t + 1) * 64);
#pragma unroll
        for (int kk = 0; kk < 64; kk += 32) {
            h8v fh[4], fl[4];
#pragma unroll
            for (int sm = 0; sm < 4; ++sm) {
                const int row = sm * 16 + lr;
                const int s8 = (((kk >> 3) + lk) ^ (row & 7)) << 3;
                fh[sm] = *(const h8v*)&sH[cur][0][row][s8];
                fl[sm] = *(const h8v*)&sH[cur][1][row][s8];
            }
            const int kc = t * 2 + (kk >> 5);
            const int jt = (j0 >> 4) + wc;
            const size_t woff = ((size_t)(jt * 12 + kc) << 9) + (lane << 3);
            const h8v bh = *(const h8v*)(wtH + woff);
            const h8v bl = *(const h8v*)(wtL + woff);
            __builtin_amdgcn_s_setprio(1);
#pragma unroll
            for (int sm = 0; sm < 4; ++sm) acc[sm] = mfma3(fh[sm], fl[sm], bh, bl, acc[sm]);
            __builtin_amdgcn_s_setprio(0);
        }
        __syncthreads();
        cur ^= 1;
    }
    const int col = j0 + wc * 16 + lr;
#pragma unroll
    for (int sm = 0; sm < 4; ++sm)
#pragma unroll
        for (int j = 0; j < 4; ++j) {
            const int row = row0 + sm * 16 + lk * 4 + j;
            if (row < N_NODESC) {
                const size_t off = (size_t)row * HD + col;
                const float v = acc[sm][j];
                h2v pr;
                pr[0] = (_Float16)v;
                pr[1] = (_Float16)(v - (float)pr[0]);
                *(h2v*)(mHL + off * 2) = pr;
            }
        }
#undef GGC_STAGE
}

// ================= dbuf LDS fused GRU (BN=128, 8 waves, wave tile 64x16) =================
__global__ __launch_bounds__(512) void gru_lds(const _Float16* __restrict__ aH,
                                               const _Float16* __restrict__ aL,
                                               const _Float16* __restrict__ hH,
                                               const _Float16* __restrict__ hL,
                                               const _Float16* __restrict__ wihH,
                                               const _Float16* __restrict__ wihL,
                                               const _Float16* __restrict__ whhH,
                                               const _Float16* __restrict__ whhL,
                                               const float* __restrict__ bih,
                                               const float* __restrict__ bhh,
                                               _Float16* __restrict__ oH,
                                               _Float16* __restrict__ oL) {
    __shared__ _Float16 sA[2][4][64][64];  // [buf][plane: aH,aL,hH,hL][row][k], 64 KB
    const int tid = threadIdx.x;
    const int wid = tid >> 6, lane = tid & 63;
    const int lr = lane & 15, lk = lane >> 4;
    const int wc = wid;                     // wave column group (16 cols, 8 waves = 128)
    const int wgid = xcd_swz(blockIdx.x, gridDim.x);
    const int row0 = (wgid / 3) << 6, j0 = (wgid % 3) << 7;
    const int col = j0 + wc * 16 + lr;      // this lane's output column
    const int tmatch = (j0 + wc * 16) >> 6; // k-tile holding this wave's h cols
    const int lctile = (wc * 16 + lr) & 63; // col within that 64-col tile
    const int sp = wid >> 1;                // staged plane (0..3)
    const int srbase = (wid & 1) << 5;      // staged row half
    const int lrow = lane >> 3, ls = lane & 7;
    const _Float16* splane = (sp == 0) ? aH : (sp == 1) ? aL : (sp == 2) ? hH : hL;

    // acc sets: 0=r (gi+gh merged), 1=z (merged), 2=n input part, 3=n hidden part
    f4v acc[4][4];                          // [set][sm]
    const f4v z4 = {0.f, 0.f, 0.f, 0.f};
#pragma unroll
    for (int g = 0; g < 4; ++g)
#pragma unroll
        for (int a = 0; a < 4; ++a) acc[g][a] = z4;
    float hold[4][4];                       // [sm][j]

#define GRU_STAGE(BUF, K0)                                                     \
    _Pragma("unroll")                                                          \
    for (int t4 = 0; t4 < 4; ++t4) {                                           \
        const int row = srbase + (t4 << 3) + lrow;                             \
        const int gk = (K0) + ((ls ^ (row & 7)) << 3);                         \
        const int grow = min(row0 + row, N_NODESC - 1);                        \
        gload_lds16(splane + (size_t)grow * HD + gk,                           \
                    &sA[BUF][sp][srbase + (t4 << 3)][0]);                      \
    }

    GRU_STAGE(0, 0);
    __syncthreads();
    int cur = 0;
    for (int t = 0; t < HD / 64; ++t) {
        if (t + 1 < HD / 64) GRU_STAGE(cur ^ 1, (t + 1) * 64);
#pragma unroll
        for (int kk = 0; kk < 64; kk += 32) {
            h8v fAh[4], fAl[4], fHh[4], fHl[4];
#pragma unroll
            for (int sm = 0; sm < 4; ++sm) {
                const int row = sm * 16 + lr;
                const int s8 = (((kk >> 3) + lk) ^ (row & 7)) << 3;
                fAh[sm] = *(const h8v*)&sA[cur][0][row][s8];
                fAl[sm] = *(const h8v*)&sA[cur][1][row][s8];
                fHh[sm] = *(const h8v*)&sA[cur][2][row][s8];
                fHl[sm] = *(const h8v*)&sA[cur][3][row][s8];
            }
            const int kc = t * 2 + (kk >> 5);
            const int jt = (j0 >> 4) + wc;
#pragma unroll
            for (int g = 0; g < 3; ++g) {
                const size_t woff = ((size_t)((g * 24 + jt) * 12 + kc) << 9) + (lane << 3);
                const h8v BiH = *(const h8v*)(wihH + woff);
                const h8v BiL = *(const h8v*)(wihL + woff);
                const h8v BhH = *(const h8v*)(whhH + woff);
                const h8v BhL = *(const h8v*)(whhL + woff);
                __builtin_amdgcn_s_setprio(1);
                if (g < 2) {
#pragma unroll
                    for (int sm = 0; sm < 4; ++sm) {
                        acc[g][sm] = mfma3(fAh[sm], fAl[sm], BiH, BiL, acc[g][sm]);
                        acc[g][sm] = mfma3(fHh[sm], fHl[sm], BhH, BhL, acc[g][sm]);
                    }
                } else {
#pragma unroll
                    for (int sm = 0; sm < 4; ++sm) {
                        acc[2][sm] = mfma3(fAh[sm], fAl[sm], BiH, BiL, acc[2][sm]);
                        acc[3][sm] = mfma3(fHh[sm], fHl[sm], BhH, BhL, acc[3][sm]);
                    }
                }
                __builtin_amdgcn_s_setprio(0);
            }
        }
        // capture hold = hH+hL at (row, col) from the staged tile (bit-identical
        // to a global read; this wave's cols are resident exactly at t == tmatch)
        if (t == tmatch) {
#pragma unroll
            for (int sm = 0; sm < 4; ++sm)
#pragma unroll
                for (int j = 0; j < 4; ++j) {
                    const int row = sm * 16 + lk * 4 + j;
                    const int sc = (((lctile >> 3) ^ (row & 7)) << 3) | (lctile & 7);
                    hold[sm][j] = (float)sA[cur][2][row][sc] + (float)sA[cur][3][row][sc];
                }
        }
        __syncthreads();
        cur ^= 1;
    }
    // epilogue: gates + GRU update (h' stays split-plane for next-step staging)
    const float brz = bih[col] + bhh[col];
    const float bzz = bih[HD + col] + bhh[HD + col];
    const float bni = bih[2 * HD + col];
    const float bnh = bhh[2 * HD + col];
#pragma unroll
    for (int sm = 0; sm < 4; ++sm)
#pragma unroll
        for (int j = 0; j < 4; ++j) {
            const int row = row0 + sm * 16 + lk * 4 + j;
            if (row < N_NODESC) {
                const size_t off = (size_t)row * HD + col;
                const float r = sigmoidf_(acc[0][sm][j] + brz);
                const float z = sigmoidf_(acc[1][sm][j] + bzz);
                const float n = tanhf((acc[2][sm][j] + bni) + r * (acc[3][sm][j] + bnh));
                const float res = (1.f - z) * n + z * hold[sm][j];
                const _Float16 hh = (_Float16)res;
                oH[off] = hh;
                oL[off] = (_Float16)(res - (float)hh);
            }
        }
#undef GRU_STAGE
}

// ================= BN stats (deterministic two-stage) =================
__global__ __launch_bounds__(384) void col_stats_partial(const float* __restrict__ X, int M,
                                                         float* __restrict__ pS,
                                                         float* __restrict__ pQ) {
    const int f = threadIdx.x;
    const int b = blockIdx.x;
    const int r0 = b * STATS_ROWS;
    const int r1 = min(r0 + STATS_ROWS, M);
    float s = 0.f, q = 0.f;
    for (int r = r0; r < r1; ++r) {
        const float v = X[(size_t)r * HD + f];
        s += v;
        q += v * v;
    }
    pS[b * HD + f] = s;
    pQ[b * HD + f] = q;
}

__global__ __launch_bounds__(384) void col_stats_h(const _Float16* __restrict__ hH,
                                                   const _Float16* __restrict__ hL, int M,
                                                   float* __restrict__ pS,
                                                   float* __restrict__ pQ) {
    const int f = threadIdx.x;
    const int b = blockIdx.x;
    const int r0 = b * STATS_ROWS;
    const int r1 = min(r0 + STATS_ROWS, M);
    float s = 0.f, q = 0.f;
    for (int r = r0; r < r1; ++r) {
        const size_t off = (size_t)r * HD + f;
        const float v = (float)hH[off] + (float)hL[off];
        s += v;
        q += v * v;
    }
    pS[b * HD + f] = s;
    pQ[b * HD + f] = q;
}

__global__ void bn_stats_final(const float* __restrict__ pS, const float* __restrict__ pQ,
                               const float* __restrict__ g, const float* __restrict__ b,
                               float* __restrict__ scale, float* __restrict__ shift, float invM) {
    const int f = threadIdx.x;
    float s = 0.f, q = 0.f;
    for (int blk = 0; blk < STATS_BLOCKS; ++blk) {
        s += pS[blk * HD + f];
        q += pQ[blk * HD + f];
    }
    const float mean = s * invM;
    const float var = q * invM - mean * mean;
    const float sc = g[f] * rsqrtf(var + BN_EPS);
    scale[f] = sc;
    shift[f] = b[f] - mean * sc;
}

// relu(X*scale+shift) -> hi/lo halves
__global__ __launch_bounds__(256) void bn_relu_split(const float* __restrict__ X,
                                                     const float* __restrict__ scale,
                                                     const float* __restrict__ shift,
                                                     _Float16* __restrict__ hH,
                                                     _Float16* __restrict__ hL) {
    const size_t i4 = (size_t)blockIdx.x * 256 + threadIdx.x;  // NH/4 exact
    const int f = (int)((i4 * 4) % HD);
    const float4 v = ((const float4*)X)[i4];
    float r0 = fmaxf(fmaf(v.x, scale[f + 0], shift[f + 0]), 0.f);
    float r1 = fmaxf(fmaf(v.y, scale[f + 1], shift[f + 1]), 0.f);
    float r2 = fmaxf(fmaf(v.z, scale[f + 2], shift[f + 2]), 0.f);
    float r3 = fmaxf(fmaf(v.w, scale[f + 3], shift[f + 3]), 0.f);
    h4v a, b;
    a[0] = (_Float16)r0; b[0] = (_Float16)(r0 - (float)a[0]);
    a[1] = (_Float16)r1; b[1] = (_Float16)(r1 - (float)a[1]);
    a[2] = (_Float16)r2; b[2] = (_Float16)(r2 - (float)a[2]);
    a[3] = (_Float16)r3; b[3] = (_Float16)(r3 - (float)a[3]);
    *(h4v*)(hH + i4 * 4) = a;
    *(h4v*)(hL + i4 * 4) = b;
}

// hfinal = relu((hH+hL)*scale + shift + relu(G*scale1 + shift1))  (fused skip)
__global__ __launch_bounds__(256) void bn_skip_relu_h2(const _Float16* __restrict__ hH,
                                                       const _Float16* __restrict__ hL,
                                                       const float* __restrict__ scale,
                                                       const float* __restrict__ shift,
                                                       const float* __restrict__ G,
                                                       const float* __restrict__ scale1,
                                                       const float* __restrict__ shift1,
                                                       float* __restrict__ out) {
    const size_t i4 = (size_t)blockIdx.x * 256 + threadIdx.x;
    const int f = (int)((i4 * 4) % HD);
    const h4v a = *(const h4v*)(hH + i4 * 4);
    const h4v b = *(const h4v*)(hL + i4 * 4);
    const float4 g = ((const float4*)G)[i4];
    const float s0 = fmaxf(fmaf(g.x, scale1[f + 0], shift1[f + 0]), 0.f);
    const float s1 = fmaxf(fmaf(g.y, scale1[f + 1], shift1[f + 1]), 0.f);
    const float s2 = fmaxf(fmaf(g.z, scale1[f + 2], shift1[f + 2]), 0.f);
    const float s3 = fmaxf(fmaf(g.w, scale1[f + 3], shift1[f + 3]), 0.f);
    float4 r;
    r.x = fmaxf(fmaf((float)a[0] + (float)b[0], scale[f + 0], shift[f + 0]) + s0, 0.f);
    r.y = fmaxf(fmaf((float)a[1] + (float)b[1], scale[f + 1], shift[f + 1]) + s1, 0.f);
    r.z = fmaxf(fmaf((float)a[2] + (float)b[2], scale[f + 2], shift[f + 2]) + s2, 0.f);
    r.w = fmaxf(fmaf((float)a[3] + (float)b[3], scale[f + 3], shift[f + 3]) + s3, 0.f);
    ((float4*)out)[i4] = r;
}

// ================= attention pooling + head =================
__global__ __launch_bounds__(64) void att_logits(const float* __restrict__ h2,
                                                 const float* __restrict__ att_w,
                                                 const float* __restrict__ att_b,
                                                 float* __restrict__ logits) {
    const int n = blockIdx.x;
    const int l = threadIdx.x;
    float acc = 0.f;
#pragma unroll
    for (int k = 0; k < HD; k += 64) acc += h2[(size_t)n * HD + k + l] * att_w[k + l];
#pragma unroll
    for (int o = 32; o > 0; o >>= 1) acc += __shfl_down(acc, o);
    if (l == 0) logits[n] = acc + att_b[0];
}

__global__ void count_graphs(const int* __restrict__ batch, int* __restrict__ counts) {
    const int n = blockIdx.x * 256 + threadIdx.x;
    if (n < N_NODESC) atomicAdd(&counts[batch[n]], 1);
}

__global__ void scan_offsets(const int* __restrict__ counts, int* __restrict__ offs) {
    __shared__ int tmp[N_GRAPHSC];
    const int t = threadIdx.x;
    tmp[t] = counts[t];
    __syncthreads();
    for (int o = 1; o < N_GRAPHSC; o <<= 1) {
        int v = (t >= o) ? tmp[t - o] : 0;
        __syncthreads();
        tmp[t] += v;
        __syncthreads();
    }
    offs[t] = tmp[t] - counts[t];
}

__global__ __launch_bounds__(384) void pool_graphs(const float* __restrict__ h2,
                                                   const float* __restrict__ logits,
                                                   const int* __restrict__ offs,
                                                   const int* __restrict__ counts,
                                                   float* __restrict__ pooled) {
    const int g = blockIdx.x;
    const int t = threadIdx.x;
    const int s = offs[g], c = counts[g], e = s + c;
    __shared__ float red[384];
    float mx = -1e30f;
    for (int n = s + t; n < e; n += 384) mx = fmaxf(mx, logits[n]);
    red[t] = mx;
    __syncthreads();
    if (t < 128) red[t] = fmaxf(red[t], fmaxf(red[t + 128], red[t + 256]));
    __syncthreads();
    for (int w = 64; w > 0; w >>= 1) {
        if (t < w) red[t] = fmaxf(red[t], red[t + w]);
        __syncthreads();
    }
    mx = red[0];
    __syncthreads();
    float sm = 0.f;
    for (int n = s + t; n < e; n += 384) sm += expf(logits[n] - mx);
    red[t] = sm;
    __syncthreads();
    if (t < 128) red[t] += red[t + 128] + red[t + 256];
    __syncthreads();
    for (int w = 64; w > 0; w >>= 1) {
        if (t < w) red[t] += red[t + w];
        __syncthreads();
    }
    const float denom = red[0];
    const float inv = (c > 0) ? 1.0f / denom : 0.0f;
    float acc = 0.f;
    for (int n = s; n < e; ++n) acc += expf(logits[n] - mx) * h2[(size_t)n * HD + t];
    pooled[(size_t)g * HD + t] = acc * inv;
}

__global__ void fc_small(const float* __restrict__ X, const float* __restrict__ W,
                         const float* __restrict__ bias, float* __restrict__ Y,
                         int K, int N) {
    const int m = blockIdx.x;
    const int n = threadIdx.x;
    if (n >= N) return;
    float acc = bias[n];
    for (int k = 0; k < K; ++k) acc += X[m * K + k] * W[k * N + n];
    Y[m * N + n] = acc;
}

__global__ void bn_small_relu(float* X, int M, int N,
                              const float* __restrict__ g, const float* __restrict__ b) {
    const int f = threadIdx.x;
    if (f >= N) return;
    float s = 0.f, q = 0.f;
    for (int r = 0; r < M; ++r) {
        const float v = X[r * N + f];
        s += v;
        q += v * v;
    }
    const float mean = s / M;
    const float var = q / M - mean * mean;
    const float sc = g[f] * rsqrtf(var + BN_EPS);
    const float sh = b[f] - mean * sc;
    for (int r = 0; r < M; ++r) X[r * N + f] = fmaxf(X[r * N + f] * sc + sh, 0.f);
}

extern "C" void kernel_launch(void* const* d_in, const int* in_sizes, int n_in,
                              void* d_out, int out_size, void* d_ws, size_t ws_size,
                              hipStream_t stream) {
    const float* x       = (const float*)d_in[0];
    const int*   eidx    = (const int*)d_in[1];
    const int*   batch   = (const int*)d_in[2];
    const float* w_in    = (const float*)d_in[3];
    const float* b_in    = (const float*)d_in[4];
    const float* bn1_g   = (const float*)d_in[5];
    const float* bn1_b   = (const float*)d_in[6];
    const float* ggc_w   = (const float*)d_in[7];
    const float* gru_wih = (const float*)d_in[8];
    const float* gru_whh = (const float*)d_in[9];
    const float* gru_bih = (const float*)d_in[10];
    const float* gru_bhh = (const float*)d_in[11];
    const float* bn2_g   = (const float*)d_in[12];
    const float* bn2_b   = (const float*)d_in[13];
    const float* att_w   = (const float*)d_in[14];
    const float* att_b   = (const float*)d_in[15];
    const float* fc1_w   = (const float*)d_in[16];
    const float* fc1_b   = (const float*)d_in[17];
    const float* bn3_g   = (const float*)d_in[18];
    const float* bn3_b   = (const float*)d_in[19];
    const float* fc2_w   = (const float*)d_in[20];
    const float* fc2_b   = (const float*)d_in[21];
    const float* bn4_g   = (const float*)d_in[22];
    const float* bn4_b   = (const float*)d_in[23];
    const float* fc3_w   = (const float*)d_in[24];
    const float* fc3_b   = (const float*)d_in[25];

    const int* src = eidx;
    const int* dst = eidx + N_EDGESC;

    // ---- workspace carve (~239 MB) ----
    const size_t NH = (size_t)N_NODESC * HD;  // 19.2M elems
    char* p = (char*)d_ws;
    float* R0 = (float*)p; p += NH * sizeof(float);   // rotating region 0
    float* R1 = (float*)p; p += NH * sizeof(float);   // rotating region 1
    float* Mreg = (float*)p; p += NH * sizeof(float); // agg halves / hfinal
    _Float16* wihP_H = (_Float16*)p; p += 3 * HD * HD * sizeof(_Float16);
    _Float16* wihP_L = (_Float16*)p; p += 3 * HD * HD * sizeof(_Float16);
    _Float16* whhP_H = (_Float16*)p; p += 3 * HD * HD * sizeof(_Float16);
    _Float16* whhP_L = (_Float16*)p; p += 3 * HD * HD * sizeof(_Float16);
    _Float16* ggcP_H = (_Float16*)p; p += (size_t)STEPSC * HD * HD * sizeof(_Float16);
    _Float16* ggcP_L = (_Float16*)p; p += (size_t)STEPSC * HD * HD * sizeof(_Float16);
    float* logits = (float*)p; p += N_NODESC * sizeof(float);
    float* pS = (float*)p; p += STATS_BLOCKS * HD * sizeof(float);
    float* pQ = (float*)p; p += STATS_BLOCKS * HD * sizeof(float);
    float* scale  = (float*)p; p += HD * sizeof(float);
    float* shift  = (float*)p; p += HD * sizeof(float);
    float* scale1 = (float*)p; p += HD * sizeof(float);
    float* shift1 = (float*)p; p += HD * sizeof(float);
    float* pooled = (float*)p; p += N_GRAPHSC * HD * sizeof(float);
    float* y1 = (float*)p; p += N_GRAPHSC * HD * sizeof(float);
    float* y2 = (float*)p; p += N_GRAPHSC * (HD / 2) * sizeof(float);
    int* counts = (int*)p; p += N_GRAPHSC * sizeof(int);
    int* offs = (int*)p; p += N_GRAPHSC * sizeof(int);
    // CSR (built once per call)
    int* deg    = (int*)p; p += N_NODESC * sizeof(int);
    int* eoffs  = (int*)p; p += (N_NODESC + 1) * sizeof(int);
    int* cursor = (int*)p; p += N_NODESC * sizeof(int);
    int* esrc   = (int*)p; p += N_EDGESC * sizeof(int);

    const int nwg = 3 * ((N_NODESC + 63) / 64);  // 3*782 = 2346 (BN=128)
    const int ew_blocks = (int)(NH / 4 / 256);   // 18750 exact

    // 0a) CSR build (graph constant across all 4 steps)
    hipMemsetAsync(deg, 0, N_NODESC * sizeof(int), stream);
    hipMemsetAsync(cursor, 0, N_NODESC * sizeof(int), stream);
    deg_count<<<(N_EDGESC + 255) / 256, 256, 0, stream>>>(dst, deg);
    scan_deg<<<1, 1024, 0, stream>>>(deg, eoffs);
    fill_csr<<<(N_EDGESC + 255) / 256, 256, 0, stream>>>(src, dst, eoffs, cursor, esrc);

    // 0b) weight prep: fragment-major packed fp16x2 (deterministic)
    pack_gru_w<<<(3 * 24 * 12 * 64 + 255) / 256, 256, 0, stream>>>(gru_wih, wihP_H, wihP_L);
    pack_gru_w<<<(3 * 24 * 12 * 64 + 255) / 256, 256, 0, stream>>>(gru_whh, whhP_H, whhP_L);
    pack_ggc_w<<<(STEPSC * 24 * 12 * 64 + 255) / 256, 256, 0, stream>>>(ggc_w, ggcP_H, ggcP_L);

    // 1) input layer (fp32) + bn1 -> h halves in R1
    gemm64<<<dim3(HD / 64, (N_NODESC + 63) / 64), 256, 0, stream>>>(x, w_in, b_in, R0,
                                                                    N_NODESC, D_INC, HD);
    col_stats_partial<<<STATS_BLOCKS, 384, 0, stream>>>(R0, N_NODESC, pS, pQ);
    bn_stats_final<<<1, 384, 0, stream>>>(pS, pQ, bn1_g, bn1_b, scale1, shift1, 1.0f / N_NODESC);
    bn_relu_split<<<ew_blocks, 256, 0, stream>>>(R0, scale1, shift1, (_Float16*)R1,
                                                 (_Float16*)R1 + NH);

    // 2) GatedGraphConv loop: ggc -> interleaved m (Oth); gather -> agg halves (Mreg);
    //    gru -> h' halves (Oth, overwrites m); rotate.
    float* Hcur = R1;
    float* Oth = R0;
    _Float16* aggH = (_Float16*)Mreg;
    _Float16* aggL = aggH + NH;
    for (int s7 = 0; s7 < STEPSC; ++s7) {
        const _Float16* hcH = (const _Float16*)Hcur;
        const _Float16* hcL = (const _Float16*)Hcur + NH;
        _Float16* mHL = (_Float16*)Oth;   // interleaved {hi,lo}, 2*NH halves
        ggc_lds<<<nwg, 512, 0, stream>>>(hcH, hcL,
                                         ggcP_H + (size_t)s7 * HD * HD,
                                         ggcP_L + (size_t)s7 * HD * HD, mHL);
        gather_agg_h<<<(N_NODESC * 24 + 255) / 256, 256, 0, stream>>>(mHL, eoffs, esrc,
                                                                      aggH, aggL);
        gru_lds<<<nwg, 512, 0, stream>>>(aggH, aggL, hcH, hcL, wihP_H, wihP_L, whhP_H, whhP_L,
                                         gru_bih, gru_bhh,
                                         (_Float16*)Oth, (_Float16*)Oth + NH);
        float* t = Hcur; Hcur = Oth; Oth = t;
    }

    // 3) bn2 + skip recompute (fused into one elementwise pass) -> hfinal (Mreg)
    const _Float16* hfH = (const _Float16*)Hcur;
    const _Float16* hfL = (const _Float16*)Hcur + NH;
    col_stats_h<<<STATS_BLOCKS, 384, 0, stream>>>(hfH, hfL, N_NODESC, pS, pQ);
    bn_stats_final<<<1, 384, 0, stream>>>(pS, pQ, bn2_g, bn2_b, scale, shift, 1.0f / N_NODESC);
    gemm64<<<dim3(HD / 64, (N_NODESC + 63) / 64), 256, 0, stream>>>(x, w_in, b_in, Oth,
                                                                    N_NODESC, D_INC, HD);
    float* hfinal = Mreg;
    bn_skip_relu_h2<<<ew_blocks, 256, 0, stream>>>(hfH, hfL, scale, shift, Oth,
                                                   scale1, shift1, hfinal);

    // 4) attention pooling
    att_logits<<<N_NODESC, 64, 0, stream>>>(hfinal, att_w, att_b, logits);
    hipMemsetAsync(counts, 0, N_GRAPHSC * sizeof(int), stream);
    count_graphs<<<(N_NODESC + 255) / 256, 256, 0, stream>>>(batch, counts);
    scan_offsets<<<1, N_GRAPHSC, 0, stream>>>(counts, offs);
    pool_graphs<<<N_GRAPHSC, 384, 0, stream>>>(hfinal, logits, offs, counts, pooled);

    // 5) MLP head
    fc_small<<<N_GRAPHSC, 384, 0, stream>>>(pooled, fc1_w, fc1_b, y1, HD, HD);
    bn_small_relu<<<1, 384, 0, stream>>>(y1, N_GRAPHSC, HD, bn3_g, bn3_b);
    fc_small<<<N_GRAPHSC, 192, 0, stream>>>(y1, fc2_w, fc2_b, y2, HD, HD / 2);
    bn_small_relu<<<1, 192, 0, stream>>>(y2, N_GRAPHSC, HD / 2, bn4_g, bn4_b);
    fc_small<<<N_GRAPHSC, 64, 0, stream>>>(y2, fc3_w, fc3_b, (float*)d_out, HD / 2, 2);
}